// Round 3
// baseline (2221.443 us; speedup 1.0000x reference)
//
#include <hip/hip_runtime.h>

// Problem: n=32, c1=c2=512, hw=4096. fp32 in/out.
// out1 = alpha*softmax_row(att) @ x2 + x1
// out2 = beta *softmax_col(att)^T-weights @ x1 + x2
// att[i][j] = <x1_i, x2_j> / (||x1_i|| ||x2_j||)
//
// Pipeline: prep converts x1/x2 to bf16 in BOTH layouts ([c][s] for the
// attention GEMM, [s][c] for the stage-2 GEMM B-operands) and accumulates
// row sum-of-squares (atomicAdd). All three GEMMs are bf16-MFMA 128x128
// tiles with XOR-swizzled LDS and fp32 accumulation/epilogue.
// Workspace audit (ws_size = 2 GiB per the 2^31-byte poison fills seen in
// both prior profiles): layout below uses 564 MB, all offsets bounds-checked.

#define N_B 32
#define C_  512
#define HW_ 4096

typedef float f32x4 __attribute__((ext_vector_type(4)));
typedef short s16x8 __attribute__((ext_vector_type(8)));   // 8 bf16 = 4 VGPRs

__device__ __forceinline__ unsigned pack_bf2(float lo, float hi) {
    unsigned a = __builtin_bit_cast(unsigned, lo);
    unsigned b = __builtin_bit_cast(unsigned, hi);
    return (a >> 16) | (b & 0xFFFF0000u);   // [hi.bf16 | lo.bf16]
}
__device__ __forceinline__ unsigned short f2bf(float f) {
    return (unsigned short)(__builtin_bit_cast(unsigned, f) >> 16);
}

// ---------------- zero the sumsq accumulators ---------------------------------
__global__ void zero_f32(float* __restrict__ p, int n) {
    int i = blockIdx.x * 256 + threadIdx.x;
    if (i < n) p[i] = 0.f;
}

// ---------------- prep: fp32 -> bf16 [c][s] + bf16 [s][c] + row sumsq ---------
// grid (16 s-tiles, 8 c-tiles, 32 n), 256 threads. Tile 64c x 256s.
__global__ __launch_bounds__(256) void prep(const float* __restrict__ x,
    unsigned short* __restrict__ xb, unsigned short* __restrict__ xbt,
    float* __restrict__ nrm)
{
    const int n = blockIdx.z, c0 = blockIdx.y * 64, s0 = blockIdx.x * 256;
    const int t = threadIdx.x, lane = t & 63, w = t >> 6;
    __shared__ unsigned short tp[64][258];   // 258 pitch: conflict-free col reads
    const float* src = x + ((size_t)n * C_ + c0) * (size_t)HW_ + s0;

#pragma unroll
    for (int i = 0; i < 16; ++i) {
        const int row = i * 4 + w;           // wave w owns rows {4i+w}
        float4 v = *(const float4*)(src + (size_t)row * HW_ + lane * 4);
        float ss = v.x * v.x + v.y * v.y + v.z * v.z + v.w * v.w;
#pragma unroll
        for (int d = 1; d < 64; d <<= 1) ss += __shfl_xor(ss, d, 64);
        if (lane == 0) atomicAdd(&nrm[n * C_ + c0 + row], ss);
        unsigned lo = pack_bf2(v.x, v.y), hi = pack_bf2(v.z, v.w);
        unsigned short* xrow = xb + ((size_t)n * C_ + c0 + row) * (size_t)HW_ + s0 + lane * 4;
        uint2 u; u.x = lo; u.y = hi;
        *(uint2*)xrow = u;
        unsigned* tl = (unsigned*)&tp[row][lane * 4];   // 4B-aligned (516*row+8*lane)
        tl[0] = lo; tl[1] = hi;
    }
    __syncthreads();
    // transpose out: thread t owns spatial row s0+t, writes 64 channels (128B)
    unsigned pk[32];
#pragma unroll
    for (int c = 0; c < 64; c += 2)
        pk[c >> 1] = (unsigned)tp[c][t] | ((unsigned)tp[c + 1][t] << 16);
    unsigned short* orow = xbt + ((size_t)n * HW_ + s0 + t) * (size_t)C_ + c0;
#pragma unroll
    for (int q = 0; q < 8; ++q) {
        uint4 u;
        u.x = pk[q * 4 + 0]; u.y = pk[q * 4 + 1];
        u.z = pk[q * 4 + 2]; u.w = pk[q * 4 + 3];
        *(uint4*)(orow + q * 8) = u;
    }
}

// ---------------- attention GEMM (bf16 in): att = D1 (x1 x2^T) D2 -------------
// 128x128 tile, BK=64, 4 waves (2x2), XOR-swizzled LDS, XCD-bijective swizzle.
__global__ __launch_bounds__(256) void attn_gemm_mfma(
    const unsigned short* __restrict__ x1b, const unsigned short* __restrict__ x2b,
    const float* __restrict__ nrm1, const float* __restrict__ nrm2,
    float* __restrict__ att)
{
    const int flat = blockIdx.x + 4 * (blockIdx.y + 4 * blockIdx.z);  // 512 wgs
    const int id   = (flat & 7) * 64 + (flat >> 3);    // bijective (512 % 8 == 0)
    const int j0 = (id & 3) * 128, m0 = ((id >> 2) & 3) * 128, n = id >> 4;
    const unsigned short* Ag = x1b + (size_t)n * C_ * HW_;
    const unsigned short* Bg = x2b + (size_t)n * C_ * HW_;

    __shared__ __align__(16) char As[128 * 128];   // 128 rows x 64 bf16
    __shared__ __align__(16) char Bs[128 * 128];

    const int t = threadIdx.x, lane = t & 63, w = t >> 6;
    const int wr = (w >> 1) * 64, wc = (w & 1) * 64;
    const int fr = lane & 15, fg = lane >> 4;

    int srow[4], soff[4], sgoff[4];
#pragma unroll
    for (int p = 0; p < 4; ++p) {
        int idx = p * 256 + t;               // 1024 16B slots per tile
        int r = idx >> 3, sl = idx & 7;
        srow[p]  = r;
        soff[p]  = r * 128 + sl * 16;        // linear LDS dest (bytes)
        sgoff[p] = (sl ^ (r & 7)) * 8;       // swizzled global chunk (elements)
    }

    uint4 a_st[4], b_st[4];
    f32x4 acc[4][4];
#pragma unroll
    for (int i = 0; i < 4; ++i)
#pragma unroll
        for (int j = 0; j < 4; ++j) acc[i][j] = (f32x4){0.f, 0.f, 0.f, 0.f};

    auto load_tiles = [&](int k0) {
#pragma unroll
        for (int p = 0; p < 4; ++p) {
            a_st[p] = *(const uint4*)(Ag + (size_t)(m0 + srow[p]) * HW_ + k0 + sgoff[p]);
            b_st[p] = *(const uint4*)(Bg + (size_t)(j0 + srow[p]) * HW_ + k0 + sgoff[p]);
        }
    };
    auto store_tiles = [&]() {
#pragma unroll
        for (int p = 0; p < 4; ++p) {
            *(uint4*)(As + soff[p]) = a_st[p];
            *(uint4*)(Bs + soff[p]) = b_st[p];
        }
    };
    auto compute = [&]() {
#pragma unroll
        for (int kk = 0; kk < 2; ++kk) {
            s16x8 af[4], bfv[4];
#pragma unroll
            for (int mi = 0; mi < 4; ++mi) {
                int row  = wr + mi * 16 + fr;
                int phys = (kk * 64 + fg * 16) ^ ((row & 7) << 4);
                af[mi] = __builtin_bit_cast(s16x8, *(const uint4*)(As + row * 128 + phys));
            }
#pragma unroll
            for (int ni = 0; ni < 4; ++ni) {
                int row  = wc + ni * 16 + fr;
                int phys = (kk * 64 + fg * 16) ^ ((row & 7) << 4);
                bfv[ni] = __builtin_bit_cast(s16x8, *(const uint4*)(Bs + row * 128 + phys));
            }
#pragma unroll
            for (int mi = 0; mi < 4; ++mi)
#pragma unroll
                for (int ni = 0; ni < 4; ++ni)
                    acc[mi][ni] = __builtin_amdgcn_mfma_f32_16x16x32_bf16(
                        af[mi], bfv[ni], acc[mi][ni], 0, 0, 0);
        }
    };

    load_tiles(0);
#pragma unroll 1
    for (int k0 = 0; k0 < HW_; k0 += 64) {
        __syncthreads();                 // prev compute done (LDS reusable)
        store_tiles();
        __syncthreads();                 // tiles visible
        if (k0 + 64 < HW_) load_tiles(k0 + 64);   // overlap with MFMA
        compute();
    }

    float i2[4];
#pragma unroll
    for (int ni = 0; ni < 4; ++ni) {
        float ss = nrm2[n * C_ + j0 + wc + ni * 16 + fr];
        i2[ni] = 1.0f / fmaxf(sqrtf(ss), 1e-12f);
    }
#pragma unroll
    for (int mi = 0; mi < 4; ++mi)
#pragma unroll
        for (int r = 0; r < 4; ++r) {
            int m = m0 + wr + mi * 16 + fg * 4 + r;
            float ss1 = nrm1[n * C_ + m];
            float i1 = 1.0f / fmaxf(sqrtf(ss1), 1e-12f);
            float* orow = att + ((size_t)n * C_ + m) * C_ + j0 + wc;
#pragma unroll
            for (int ni = 0; ni < 4; ++ni)
                orow[ni * 16 + fr] = acc[mi][ni][r] * i1 * i2[ni];
        }
}

// ---------------- column softmax (over i), writes bf16 attn2[n][j][i] ---------
__global__ void col_softmax_bf16(const float* __restrict__ att,
                                 unsigned short* __restrict__ attn2b) {
    const int n  = blockIdx.y;
    const int j0 = blockIdx.x * 64;
    const int t  = threadIdx.x;
    const int col = j0 + (t & 63);
    const int sl  = t >> 6;                      // 0..3
    const float* base = att + (size_t)n * C_ * C_;

    float m = -INFINITY, l = 0.f;
#pragma unroll 4
    for (int i = sl * 128; i < sl * 128 + 128; ++i) {
        float v = base[(size_t)i * C_ + col];
        float mn = fmaxf(m, v);
        l = l * __expf(m - mn) + __expf(v - mn);
        m = mn;
    }
    __shared__ float ms[4][64], ls[4][64];
    ms[sl][t & 63] = m;
    ls[sl][t & 63] = l;
    __syncthreads();
    float M = fmaxf(fmaxf(ms[0][t & 63], ms[1][t & 63]),
                    fmaxf(ms[2][t & 63], ms[3][t & 63]));
    float L = 0.f;
#pragma unroll
    for (int s = 0; s < 4; ++s) L += ls[s][t & 63] * __expf(ms[s][t & 63] - M);
    const float inv = 1.0f / L;
    unsigned short* outp = attn2b + ((size_t)n * C_ + col) * C_;
#pragma unroll 4
    for (int i = sl * 128; i < sl * 128 + 128; ++i)
        outp[i] = f2bf(__expf(base[(size_t)i * C_ + col] - M) * inv);
}

// ---------------- row softmax, rewrites att row IN PLACE as bf16 (pitch 1024) -
__global__ void row_softmax_bf16(float* __restrict__ att) {
    const size_t row = blockIdx.x;               // n*512 + i
    float* p = att + row * (size_t)C_;
    const int t = threadIdx.x;                   // 256
    float2 v = *(const float2*)(p + 2 * t);
    __shared__ float red[256];
    red[t] = fmaxf(v.x, v.y);
    __syncthreads();
    for (int s = 128; s > 0; s >>= 1) {
        if (t < s) red[t] = fmaxf(red[t], red[t + s]);
        __syncthreads();
    }
    const float M = red[0];
    __syncthreads();
    float e0 = __expf(v.x - M), e1 = __expf(v.y - M);
    red[t] = e0 + e1;
    __syncthreads();
    for (int s = 128; s > 0; s >>= 1) {
        if (t < s) red[t] += red[t + s];
        __syncthreads();
    }
    const float inv = 1.0f / red[0];
    // all reads of this row happened before the first barrier -> no hazard
    ((unsigned*)p)[t] = pack_bf2(e0 * inv, e1 * inv);
}

// ---------------- stage-2 GEMM + epilogue: out = sc*(A@B) + X -----------------
// A: bf16 attention weights [512 x 512], row-major pitch pitchA (k-inner).
// B: bf16 transposed copy xbt [4096 s][512 k] (k-inner!) -> same staging as A.
// M=512 (i), N=4096 (s), K=512. 128x128 tile, BK=64, 8 K-steps, 4 waves.
__global__ __launch_bounds__(256) void gemm_epi_mfma(
    const unsigned short* __restrict__ Aall, const int pitchA,
    const unsigned short* __restrict__ Bt,
    const float* __restrict__ Xall, const float* __restrict__ scal,
    float* __restrict__ outAll)
{
    const int flat = blockIdx.x + 32 * (blockIdx.y + 4 * blockIdx.z);  // 4096 wgs
    const int id   = (flat & 7) * 512 + (flat >> 3);   // bijective XCD swizzle
    const int s0 = (id & 31) * 128, m0 = ((id >> 5) & 3) * 128, n = id >> 7;
    const unsigned short* Ag = Aall + (size_t)n * C_ * pitchA;
    const unsigned short* Bg = Bt   + (size_t)n * HW_ * C_;
    const float* Xg = Xall + (size_t)n * C_ * HW_;
    float* out = outAll + (size_t)n * C_ * HW_;

    __shared__ __align__(16) char As[128 * 128];
    __shared__ __align__(16) char Bs[128 * 128];

    const int t = threadIdx.x, lane = t & 63, w = t >> 6;
    const int wr = (w >> 1) * 64, wc = (w & 1) * 64;
    const int fr = lane & 15, fg = lane >> 4;

    int srow[4], soff[4], sgoff[4];
#pragma unroll
    for (int p = 0; p < 4; ++p) {
        int idx = p * 256 + t;
        int r = idx >> 3, sl = idx & 7;
        srow[p]  = r;
        soff[p]  = r * 128 + sl * 16;
        sgoff[p] = (sl ^ (r & 7)) * 8;
    }

    uint4 a_st[4], b_st[4];
    f32x4 acc[4][4];
#pragma unroll
    for (int i = 0; i < 4; ++i)
#pragma unroll
        for (int j = 0; j < 4; ++j) acc[i][j] = (f32x4){0.f, 0.f, 0.f, 0.f};

    auto load_tiles = [&](int k0) {
#pragma unroll
        for (int p = 0; p < 4; ++p) {
            a_st[p] = *(const uint4*)(Ag + (size_t)(m0 + srow[p]) * pitchA + k0 + sgoff[p]);
            b_st[p] = *(const uint4*)(Bg + (size_t)(s0 + srow[p]) * C_ + k0 + sgoff[p]);
        }
    };
    auto store_tiles = [&]() {
#pragma unroll
        for (int p = 0; p < 4; ++p) {
            *(uint4*)(As + soff[p]) = a_st[p];
            *(uint4*)(Bs + soff[p]) = b_st[p];
        }
    };
    auto compute = [&]() {
#pragma unroll
        for (int kk = 0; kk < 2; ++kk) {
            s16x8 af[4], bfv[4];
#pragma unroll
            for (int mi = 0; mi < 4; ++mi) {
                int row  = wr + mi * 16 + fr;
                int phys = (kk * 64 + fg * 16) ^ ((row & 7) << 4);
                af[mi] = __builtin_bit_cast(s16x8, *(const uint4*)(As + row * 128 + phys));
            }
#pragma unroll
            for (int ni = 0; ni < 4; ++ni) {
                int row  = wc + ni * 16 + fr;
                int phys = (kk * 64 + fg * 16) ^ ((row & 7) << 4);
                bfv[ni] = __builtin_bit_cast(s16x8, *(const uint4*)(Bs + row * 128 + phys));
            }
#pragma unroll
            for (int mi = 0; mi < 4; ++mi)
#pragma unroll
                for (int ni = 0; ni < 4; ++ni)
                    acc[mi][ni] = __builtin_amdgcn_mfma_f32_16x16x32_bf16(
                        af[mi], bfv[ni], acc[mi][ni], 0, 0, 0);
        }
    };

    load_tiles(0);
#pragma unroll 1
    for (int ks = 0; ks < 8; ++ks) {
        __syncthreads();
        store_tiles();
        __syncthreads();
        if (ks < 7) load_tiles((ks + 1) * 64);   // overlap with MFMA
        compute();
    }

    const float sc = scal[0];
#pragma unroll
    for (int mi = 0; mi < 4; ++mi)
#pragma unroll
        for (int r = 0; r < 4; ++r) {
            int m = m0 + wr + mi * 16 + fg * 4 + r;
            const float* xrow = Xg + (size_t)m * HW_ + s0 + wc;
            float*       orow = out + (size_t)m * HW_ + s0 + wc;
#pragma unroll
            for (int ni = 0; ni < 4; ++ni)
                orow[ni * 16 + fr] = fmaf(sc, acc[mi][ni][r], xrow[ni * 16 + fr]);
        }
}

extern "C" void kernel_launch(void* const* d_in, const int* in_sizes, int n_in,
                              void* d_out, int out_size, void* d_ws, size_t ws_size,
                              hipStream_t stream) {
    const float* x1    = (const float*)d_in[0];
    const float* x2    = (const float*)d_in[1];
    const float* alpha = (const float*)d_in[2];
    const float* beta  = (const float*)d_in[3];
    float* out = (float*)d_out;

    // Workspace layout (~564 MB of the 2 GiB workspace):
    //   nrm1,nrm2 : 2 x 16384 f32 sumsq accumulators
    //   att       : 32 MB fp32 attention (row-softmax rewrites in place as bf16)
    //   attn2b    : 16 MB bf16 col-softmaxed weights [n][j][i]
    //   x1b,x2b   : 128 MB each, bf16 [c][s]   (attention GEMM operands)
    //   x1bt,x2bt : 128 MB each, bf16 [s][c]   (stage-2 GEMM B operands)
    float* nrm1 = (float*)d_ws;
    float* nrm2 = nrm1 + (size_t)N_B * C_;
    float* att  = nrm2 + (size_t)N_B * C_;
    unsigned short* attn2b = (unsigned short*)(att + (size_t)N_B * C_ * C_);
    unsigned short* x1b  = attn2b + (size_t)N_B * C_ * C_;
    unsigned short* x2b  = x1b  + (size_t)N_B * C_ * HW_;
    unsigned short* x1bt = x2b  + (size_t)N_B * C_ * HW_;
    unsigned short* x2bt = x1bt + (size_t)N_B * C_ * HW_;
    unsigned short* attn1b = (unsigned short*)att;       // after row_softmax, pitch 1024
    float* out1 = out;
    float* out2 = out + (size_t)N_B * C_ * HW_;

    zero_f32<<<(2 * N_B * C_ + 255) / 256, 256, 0, stream>>>(nrm1, 2 * N_B * C_);
    prep<<<dim3(16, 8, N_B), 256, 0, stream>>>(x1, x1b, x1bt, nrm1);
    prep<<<dim3(16, 8, N_B), 256, 0, stream>>>(x2, x2b, x2bt, nrm2);

    attn_gemm_mfma<<<dim3(4, 4, N_B), 256, 0, stream>>>(x1b, x2b, nrm1, nrm2, att);

    col_softmax_bf16<<<dim3(8, N_B), 256, 0, stream>>>(att, attn2b);
    row_softmax_bf16<<<N_B * C_, 256, 0, stream>>>(att);

    // out2 = beta * (attn2 @ x1) + x2   (A = attn2b pitch 512, B = x1bt)
    gemm_epi_mfma<<<dim3(32, 4, N_B), 256, 0, stream>>>(attn2b, C_, x1bt, x2, beta, out2);
    // out1 = alpha * (attn1 @ x2) + x1  (A = in-place bf16 att pitch 1024, B = x2bt)
    gemm_epi_mfma<<<dim3(32, 4, N_B), 256, 0, stream>>>(attn1b, 2 * C_, x2bt, x1, alpha, out1);
}